// Round 9
// baseline (431.750 us; speedup 1.0000x reference)
//
#include <hip/hip_runtime.h>

// Problem constants
#define B_  4
#define H_  12
#define L_  1024
#define DK_ 64
#define GH_ 8      // global attention heads
#define WS_ 9      // gru window steps (INIT_VAL+1)

// attention LDS: sK [64][64]bf16 swz + sVT [64][64]bf16 swz + sP 4 waves x [16][64]bf16
#define ATTN_LDS_BYTES (3 * 64 * 64 * 2)   // 24,576
// GRU LDS: W_hh bf16 [192][64] swz (24576) + XGP bf16 [136 pos][192 j] stride 392B (53312)
//        + b_ih f32 [192] (768) + b_hh f32 [192] (768)  -> 79,424  (<80K: 2 blocks/CU)
#define GRU_W_OFF    0
#define GRU_XGP_OFF  24576
#define GRU_BIH_OFF  77888
#define GRU_BHH_OFF  78656
#define GRU_LDS_BYTES 79424
#define XGP_STRIDE   392   // bytes per pos-row (192 bf16 + 4B pad)

#define MB_WORDS (B_ * L_ * 16)            // 65,536 u64 words = 512 KB

typedef __attribute__((ext_vector_type(8))) short short8;
typedef __attribute__((ext_vector_type(4))) float f32x4;

#define MFMA_BF16(a, b, c) __builtin_amdgcn_mfma_f32_16x16x32_bf16((a), (b), (c), 0, 0, 0)

__device__ __forceinline__ unsigned short f2bf(float f) {  // f32 -> bf16 bits, RNE
  unsigned int u = __builtin_bit_cast(unsigned int, f);
  u += 0x7fffu + ((u >> 16) & 1u);
  return (unsigned short)(u >> 16);
}
__device__ __forceinline__ float bf2f(unsigned short s) {  // bf16 bits -> f32 (exact)
  return __builtin_bit_cast(float, ((unsigned int)s) << 16);
}
__device__ __forceinline__ short8 pack8(const float4 a, const float4 b) {
  short8 r;
  r[0] = (short)f2bf(a.x); r[1] = (short)f2bf(a.y);
  r[2] = (short)f2bf(a.z); r[3] = (short)f2bf(a.w);
  r[4] = (short)f2bf(b.x); r[5] = (short)f2bf(b.y);
  r[6] = (short)f2bf(b.z); r[7] = (short)f2bf(b.w);
  return r;
}
__device__ __forceinline__ uint4 packrow16(const float4 a, const float4 b) {
  uint4 r;
  r.x = (unsigned)f2bf(a.x) | ((unsigned)f2bf(a.y) << 16);
  r.y = (unsigned)f2bf(a.z) | ((unsigned)f2bf(a.w) << 16);
  r.z = (unsigned)f2bf(b.x) | ((unsigned)f2bf(b.y) << 16);
  r.w = (unsigned)f2bf(b.z) | ((unsigned)f2bf(b.w) << 16);
  return r;
}
// extract bf16 #r (compile-time r, 0..3) of a uint2 as f32
__device__ __forceinline__ float bfget(const uint2 u, const int r) {
  const unsigned d = (r & 2) ? u.y : u.x;
  return (r & 1) ? __builtin_bit_cast(float, d & 0xffff0000u)
                 : __builtin_bit_cast(float, d << 16);
}
// gate-row permutation: within one 64-row gate block, permuted row rho=(dt,m)
// holds actual row pi = ((dt&1)<<5) + ((m>>2)<<3) + ((dt>>1)<<2) + (m&3).
// Chosen so the GRU recurrence's produced h-dims per lane == the next step's
// B-fragment dims per lane (h hand-off is pure in-register; no LDS/shuffle).
__device__ __forceinline__ int pi_row(const int dt, const int m) {
  return ((dt & 1) << 5) + ((m >> 2) << 3) + ((dt >> 1) << 2) + (m & 3);
}

// ---------------- mask bit-pack: int32 [B][L][L] -> u64 bits [B*L][16] -----
__global__ __launch_bounds__(256) void maskpack_kernel(
    const int* __restrict__ mask, unsigned long long* __restrict__ mb)
{
  const int idx = blockIdx.x * 256 + threadIdx.x;   // word id, 0..65535
  const int* src = mask + (size_t)idx * 64;
  unsigned long long bits = 0ull;
#pragma unroll
  for (int i = 0; i < 16; ++i) {
    const int4 m4 = *(const int4*)(src + i * 4);
    if (m4.x) bits |= 1ull << (i * 4 + 0);
    if (m4.y) bits |= 1ull << (i * 4 + 1);
    if (m4.z) bits |= 1ull << (i * 4 + 2);
    if (m4.w) bits |= 1ull << (i * 4 + 3);
  }
  mb[idx] = bits;
}

// ---------------- Global attention (heads 0..7), bf16 MFMA flash -----------
// grid (L/64, 8, B), block 256 (4 waves). Raw s_barrier + explicit lgkmcnt(0)
// (NOT __syncthreads) so the 1-deep K/V/mask register prefetch stays in
// flight across barriers (compiler's vmcnt(0)-drain before s_barrier was the
// round-7 stall). V staged as paired-row u32 writes (conflict-free).
__global__ __launch_bounds__(256) void attn_kernel(
    const float* __restrict__ q, const float* __restrict__ k,
    const float* __restrict__ v, const int* __restrict__ mask,
    const unsigned long long* __restrict__ mb, const int use_bits,
    float* __restrict__ out)
{
  extern __shared__ char smc[];
  char* sK  = smc;            // [64][64] bf16, swizzled rows (128B)
  char* sVT = smc + 8192;     // [64][64] bf16: VT[d][kcol], swizzled rows
  char* sP  = smc + 16384;    // wave w: [16][64] bf16 at +2048*w

  const int tid = threadIdx.x;
  const int q0 = blockIdx.x * 64;
  const int h  = blockIdx.y;
  const int b  = blockIdx.z;

  const int w  = tid >> 6;
  const int ln = tid & 63;
  const int lg = ln >> 4;        // lane group 0..3
  const int c  = ln & 15;        // lane col 0..15

  const size_t hbase = ((size_t)b * H_ + h) * L_ * DK_;
  const float* kp = k + hbase;
  const float* vp = v + hbase;
  const int*   mp = mask + (size_t)b * L_ * L_;
  const unsigned long long* mbp = mb + (size_t)b * L_ * 16;

  // Q A-fragments in registers: rows q0 + w*16 + c, d = kt*32 + lg*8 + i
  short8 qa[2];
  {
    const float* qrow = q + hbase + (size_t)(q0 + w * 16 + c) * DK_ + lg * 8;
#pragma unroll
    for (int kt = 0; kt < 2; ++kt) {
      const float4 f0 = *(const float4*)(qrow + kt * 32);
      const float4 f1 = *(const float4*)(qrow + kt * 32 + 4);
      qa[kt] = pack8(f0, f1);
    }
  }

  char* sPw = sP + w * 2048;

  f32x4 o_[4];
#pragma unroll
  for (int nt = 0; nt < 4; ++nt) { o_[nt][0] = 0.f; o_[nt][1] = 0.f; o_[nt][2] = 0.f; o_[nt][3] = 0.f; }
  float mrun[4], lrun[4];
#pragma unroll
  for (int r = 0; r < 4; ++r) { mrun[r] = -1e30f; lrun[r] = 0.f; }

  // staging roles: K: row rr, 16-col chunk c16.  V: row-pair r2, 8-col chunk j0v.
  const int rr  = tid >> 2;
  const int c16 = (tid & 3) << 4;
  const int r2  = (tid & 31) << 1;
  const int j0v = (tid >> 5) << 3;

  // ---- prologue: prefetch tile 0 into registers ----
  float4 kreg[4], vreg[4];
  unsigned long long mreg[4];
  {
    const float* ksrc = kp + (size_t)rr * DK_ + c16;
    kreg[0] = *(const float4*)(ksrc);      kreg[1] = *(const float4*)(ksrc + 4);
    kreg[2] = *(const float4*)(ksrc + 8);  kreg[3] = *(const float4*)(ksrc + 12);
    const float* vsrc = vp + (size_t)r2 * DK_ + j0v;
    vreg[0] = *(const float4*)(vsrc);       vreg[1] = *(const float4*)(vsrc + 4);
    vreg[2] = *(const float4*)(vsrc + 64);  vreg[3] = *(const float4*)(vsrc + 68);
    if (use_bits) {
#pragma unroll
      for (int r = 0; r < 4; ++r)
        mreg[r] = mbp[(size_t)(q0 + w * 16 + lg * 4 + r) * 16 + 0];
    }
  }

  for (int kt0 = 0; kt0 < 16; ++kt0) {
    // ---- write staged tile (registers) to LDS, swizzled ----
    {
      const int kb = rr * 128 + c16 * 2;
      const int sw = (rr & 7) << 4;
      *(uint4*)(sK + ((kb) ^ sw))      = packrow16(kreg[0], kreg[1]);
      *(uint4*)(sK + ((kb + 16) ^ sw)) = packrow16(kreg[2], kreg[3]);
      const float va_[8] = {vreg[0].x, vreg[0].y, vreg[0].z, vreg[0].w,
                            vreg[1].x, vreg[1].y, vreg[1].z, vreg[1].w};
      const float vb_[8] = {vreg[2].x, vreg[2].y, vreg[2].z, vreg[2].w,
                            vreg[3].x, vreg[3].y, vreg[3].z, vreg[3].w};
#pragma unroll
      for (int j = 0; j < 8; ++j) {
        const int d = j0v + j;
        const unsigned u32v = (unsigned)f2bf(va_[j]) | ((unsigned)f2bf(vb_[j]) << 16);
        *(unsigned*)(sVT + ((d * 128 + r2 * 2) ^ ((d & 7) << 4))) = u32v;
      }
    }
    // writes visible to all waves; do NOT drain vmcnt (prefetch stays in flight)
    asm volatile("s_waitcnt lgkmcnt(0)" ::: "memory");
    __builtin_amdgcn_s_barrier();

    // capture this tile's mask words, then issue next tile's loads
    unsigned long long mcur[4];
#pragma unroll
    for (int r = 0; r < 4; ++r) mcur[r] = mreg[r];
    {
      const int ktn = (kt0 + 1) & 15;
      const float* ksrc = kp + (size_t)(ktn * 64 + rr) * DK_ + c16;
      kreg[0] = *(const float4*)(ksrc);      kreg[1] = *(const float4*)(ksrc + 4);
      kreg[2] = *(const float4*)(ksrc + 8);  kreg[3] = *(const float4*)(ksrc + 12);
      const float* vsrc = vp + (size_t)(ktn * 64 + r2) * DK_ + j0v;
      vreg[0] = *(const float4*)(vsrc);       vreg[1] = *(const float4*)(vsrc + 4);
      vreg[2] = *(const float4*)(vsrc + 64);  vreg[3] = *(const float4*)(vsrc + 68);
      if (use_bits) {
#pragma unroll
        for (int r = 0; r < 4; ++r)
          mreg[r] = mbp[(size_t)(q0 + w * 16 + lg * 4 + r) * 16 + ktn];
      }
    }

    // ---- S = Q K^T : 4 N-tiles x 2 K-chunks ----
    f32x4 acc[4];
#pragma unroll
    for (int nt = 0; nt < 4; ++nt) {
      acc[nt][0] = 0.f; acc[nt][1] = 0.f; acc[nt][2] = 0.f; acc[nt][3] = 0.f;
#pragma unroll
      for (int kt = 0; kt < 2; ++kt) {
        const int off = (((nt * 16 + c) * 128 + kt * 64 + lg * 16) ^ ((c & 7) << 4));
        const short8 bk = __builtin_bit_cast(short8, *(const uint4*)(sK + off));
        acc[nt] = MFMA_BF16(qa[kt], bk, acc[nt]);
      }
    }

    // ---- mask + online softmax (rows lg*4+r; 16 c-lanes share a row) ----
#pragma unroll
    for (int r = 0; r < 4; ++r) {
      bool k0_, k1_, k2_, k3_;
      if (use_bits) {
        const unsigned long long mword = mcur[r];
        k0_ = (mword >> (c)) & 1ull;
        k1_ = (mword >> (16 + c)) & 1ull;
        k2_ = (mword >> (32 + c)) & 1ull;
        k3_ = (mword >> (48 + c)) & 1ull;
      } else {
        const int qr = q0 + w * 16 + lg * 4 + r;
        const int* mrow = mp + (size_t)qr * L_ + kt0 * 64 + c;
        k0_ = mrow[0] != 0; k1_ = mrow[16] != 0; k2_ = mrow[32] != 0; k3_ = mrow[48] != 0;
      }
      const float s0_ = k0_ ? acc[0][r] * 0.125f : -1e12f;
      const float s1_ = k1_ ? acc[1][r] * 0.125f : -1e12f;
      const float s2_ = k2_ ? acc[2][r] * 0.125f : -1e12f;
      const float s3_ = k3_ ? acc[3][r] * 0.125f : -1e12f;
      float mt = fmaxf(fmaxf(s0_, s1_), fmaxf(s2_, s3_));
#pragma unroll
      for (int off = 1; off < 16; off <<= 1) mt = fmaxf(mt, __shfl_xor(mt, off));
      const float mnew = fmaxf(mrun[r], mt);
      const float p0 = __expf(s0_ - mnew);
      const float p1 = __expf(s1_ - mnew);
      const float p2 = __expf(s2_ - mnew);
      const float p3 = __expf(s3_ - mnew);
      float pt = p0 + p1 + p2 + p3;
#pragma unroll
      for (int off = 1; off < 16; off <<= 1) pt += __shfl_xor(pt, off);
      const float scale = __expf(mrun[r] - mnew);
      mrun[r] = mnew;
      lrun[r] = lrun[r] * scale + pt;
      o_[0][r] *= scale; o_[1][r] *= scale; o_[2][r] *= scale; o_[3][r] *= scale;
      const int prow = lg * 4 + r;
      const int pb = prow * 128;
      const int psw = (prow & 7) << 4;
      *(unsigned short*)(sPw + ((pb + (c * 2)) ^ psw))       = f2bf(p0);
      *(unsigned short*)(sPw + ((pb + (16 + c) * 2) ^ psw))  = f2bf(p1);
      *(unsigned short*)(sPw + ((pb + (32 + c) * 2) ^ psw))  = f2bf(p2);
      *(unsigned short*)(sPw + ((pb + (48 + c) * 2) ^ psw))  = f2bf(p3);
    }

    // ---- O += P V  (A = P from wave-private LDS, B = V^T) ----
#pragma unroll
    for (int kt = 0; kt < 2; ++kt) {
      const int aoff = ((c * 128 + kt * 64 + lg * 16) ^ ((c & 7) << 4));
      const short8 pa = __builtin_bit_cast(short8, *(const uint4*)(sPw + aoff));
#pragma unroll
      for (int nt = 0; nt < 4; ++nt) {
        const int boff = (((nt * 16 + c) * 128 + kt * 64 + lg * 16) ^ ((c & 7) << 4));
        const short8 bv = __builtin_bit_cast(short8, *(const uint4*)(sVT + boff));
        o_[nt] = MFMA_BF16(pa, bv, o_[nt]);
      }
    }
    // drain LDS ops (reads consumed; keeps vmcnt untouched), then barrier
    asm volatile("s_waitcnt lgkmcnt(0)" ::: "memory");
    __builtin_amdgcn_s_barrier();
  }

  // ---- finalize: divide by l, store f32 ----
  float* op = out + (((size_t)b * 24 + h) * L_ + q0 + w * 16) * DK_;
#pragma unroll
  for (int r = 0; r < 4; ++r) {
    const float inv = 1.f / lrun[r];
#pragma unroll
    for (int nt = 0; nt < 4; ++nt)
      op[(size_t)(lg * 4 + r) * DK_ + nt * 16 + c] = o_[nt][r] * inv;
  }
}

// ---------------- GRU (heads 8..23), bf16 MFMA, permuted-gate layout --------
// grid (L/128, 16, B), block 512 (8 waves), 79.4KB LDS -> 2 blocks/CU
// (4 waves/SIMD). SWAPPED MFMA: A = W (j-tiles), B = h/v (pos) so each lane
// owns ONE sequence (seq = seqB + c). Gate rows of W_ih/W_hh (and their
// biases) are permuted by pi_row so that the h produced in C-fragments is
// exactly the next step's B-fragment: the 9-step recurrence has NO LDS
// writes, NO shuffles, NO barriers - only independent W/XG LDS reads.
// Bias folding (round-8 bugfix): XGP folds b_ih (all gates) + b_hh (r,z only
// - additive inside sigmoid, fold is exact). b_hh_n must NOT be folded:
// n = tanh(xn + r*(h.W_n + b_hh_n)) multiplies b_hh_n by r. Kept in regs.
__global__ __launch_bounds__(512, 4) void gru_kernel(
    const float* __restrict__ value, const float* __restrict__ wih_g,
    const float* __restrict__ whh_g, const float* __restrict__ bih_g,
    const float* __restrict__ bhh_g, float* __restrict__ out)
{
  extern __shared__ char smc[];
  char*  sW   = smc + GRU_W_OFF;       // W_hh bf16 swz [192][64], permuted rows
  char*  sXGP = smc + GRU_XGP_OFF;     // bf16 [136 pos][192 j], stride 392B
  float* sBih = (float*)(smc + GRU_BIH_OFF);  // [192]
  float* sBhh = (float*)(smc + GRU_BHH_OFF);  // [192]

  const int tid  = threadIdx.x;
  const int l0   = blockIdx.x * 128;
  const int gset = blockIdx.y >> 2;
  const int vh   = blockIdx.y & 3;
  const int b    = blockIdx.z;

  const float* vp   = value + (((size_t)b * H_ + GH_ + vh) * L_) * DK_;
  const float* wih  = wih_g + (size_t)gset * 192 * DK_;
  const float* whh  = whh_g + (size_t)gset * 192 * DK_;
  const float* bihp = bih_g + gset * 192;
  const float* bhhp = bhh_g + gset * 192;

  if (tid < 192) { sBih[tid] = bihp[tid]; sBhh[tid] = bhhp[tid]; }

  // stage W_hh -> bf16 swizzled LDS, rows in PERMUTED order
  for (int cid = tid; cid < 1536; cid += 512) {   // 192 rows * 8 chunks(16B)
    const int row = cid >> 3, ch = cid & 7;       // row = permuted-space index
    const int g = row >> 6, dt = (row >> 4) & 3, m = row & 15;
    const int arow = g * 64 + pi_row(dt, m);
    const float* wp = whh + (size_t)arow * 64 + ch * 8;
    const float4 w0 = *(const float4*)wp;
    const float4 w1 = *(const float4*)(wp + 4);
    *(uint4*)(sW + ((row * 128 + ch * 16) ^ ((row & 7) << 4))) = packrow16(w0, w1);
  }
  __syncthreads();

  const int w  = tid >> 6;
  const int ln = tid & 63;
  const int lg = ln >> 4;
  const int c  = ln & 15;

  // ---- phase 1 (swapped): XGP[pos][j] = W_ih[aj]·v[pos] + b_ih (+ b_hh r,z) --
  for (int t = w; t < 108; t += 8) {
    const int jt = t % 12, pt = t / 12;
    const int g = jt >> 2, dt = jt & 3;
    // A = W_ih row (permuted) aj, dims lg*8..+7 and 32+lg*8..+7
    const int aj = g * 64 + pi_row(dt, c);
    const float* wb = wih + (size_t)aj * 64 + lg * 8;
    const short8 aA = pack8(*(const float4*)(wb),      *(const float4*)(wb + 4));
    const short8 aB = pack8(*(const float4*)(wb + 32), *(const float4*)(wb + 36));
    // B = v row pos (zero past L)
    const int pos = pt * 16 + c;
    const int gp  = l0 + pos;
    const bool valid = gp < L_;
    float4 z4; z4.x = 0.f; z4.y = 0.f; z4.z = 0.f; z4.w = 0.f;
    const float* va = vp + (size_t)gp * 64 + lg * 8;
    const short8 bA = pack8(valid ? *(const float4*)(va)      : z4,
                            valid ? *(const float4*)(va + 4)  : z4);
    const short8 bB = pack8(valid ? *(const float4*)(va + 32) : z4,
                            valid ? *(const float4*)(va + 36) : z4);
    f32x4 acc = {0.f, 0.f, 0.f, 0.f};
    acc = MFMA_BF16(aA, bA, acc);
    acc = MFMA_BF16(aB, bB, acc);
    // biases: D rows m = lg*4+r -> actual j contiguous in r
    const int jb = g * 64 + ((dt & 1) << 5) + (lg << 3) + ((dt >> 1) << 2);
    const f32x4 bi = *(const f32x4*)(sBih + jb);
    const f32x4 bh4 = *(const f32x4*)(sBhh + jb);
    const float foldh = (g < 2) ? 1.f : 0.f;   // fold b_hh only for r,z gates
    if (pos < 136) {
      uint2 pk;
      pk.x = (unsigned)f2bf(acc[0] + bi[0] + foldh * bh4[0]) |
             ((unsigned)f2bf(acc[1] + bi[1] + foldh * bh4[1]) << 16);
      pk.y = (unsigned)f2bf(acc[2] + bi[2] + foldh * bh4[2]) |
             ((unsigned)f2bf(acc[3] + bi[3] + foldh * bh4[3]) << 16);
      *(uint2*)(sXGP + pos * XGP_STRIDE + jt * 32 + lg * 8) = pk;
    }
  }
  __syncthreads();

  // ---- recurrence: 9 steps, zero LDS writes / shuffles / barriers ----
  const int seqB = w * 16;
  const int xrow0 = seqB + c;            // this lane's sequence (local pos)

  // b_hh_n for this lane's n-gate dims (actual rows 128 + dact), loop-invariant
  f32x4 bhn[4];
#pragma unroll
  for (int dt = 0; dt < 4; ++dt)
    bhn[dt] = *(const f32x4*)(sBhh + 128 + ((dt & 1) << 5) + (lg << 3) + ((dt >> 1) << 2));

  float hfr[4][4];                       // [dt][r]: actual dim pi_row(dt, lg*4+r)
#pragma unroll
  for (int dt = 0; dt < 4; ++dt)
#pragma unroll
    for (int r = 0; r < 4; ++r) hfr[dt][r] = 0.f;

  short8 bh[2], bl[2];                   // h B-frags (hi/lo), built in-register

#pragma unroll
  for (int ts = 0; ts < WS_; ++ts) {
    // XG reads: 12 independent b64 (row = own seq + ts)
    uint2 xg[12];
#pragma unroll
    for (int jt = 0; jt < 12; ++jt)
      xg[jt] = *(const uint2*)(sXGP + (xrow0 + ts) * XGP_STRIDE + jt * 32 + lg * 8);

    f32x4 acc[12];
    if (ts == 0) {
#pragma unroll
      for (int jt = 0; jt < 12; ++jt) {
        acc[jt][0] = 0.f; acc[jt][1] = 0.f; acc[jt][2] = 0.f; acc[jt][3] = 0.f;
      }
    } else {
#pragma unroll
      for (int jt = 0; jt < 12; ++jt) {
        acc[jt][0] = 0.f; acc[jt][1] = 0.f; acc[jt][2] = 0.f; acc[jt][3] = 0.f;
#pragma unroll
        for (int kt = 0; kt < 2; ++kt) {
          const int wo = (((jt * 16 + c) * 128 + kt * 64 + lg * 16) ^ ((c & 7) << 4));
          const short8 wv = __builtin_bit_cast(short8, *(const uint4*)(sW + wo));
          acc[jt] = MFMA_BF16(wv, bh[kt], acc[jt]);
          acc[jt] = MFMA_BF16(wv, bl[kt], acc[jt]);
        }
      }
    }

    // gates + h update (slots aligned across r/z/n by pi_row)
#pragma unroll
    for (int dt = 0; dt < 4; ++dt) {
#pragma unroll
      for (int r = 0; r < 4; ++r) {
        const float xr = bfget(xg[dt], r);
        const float xz = bfget(xg[4 + dt], r);
        const float xn = bfget(xg[8 + dt], r);
        const float rr_ = __builtin_amdgcn_rcpf(1.f + __expf(-(xr + acc[dt][r])));
        const float zz  = __builtin_amdgcn_rcpf(1.f + __expf(-(xz + acc[4 + dt][r])));
        const float hn  = acc[8 + dt][r] + bhn[dt][r];     // b_hh_n NOT folded
        const float e2  = __expf(2.f * (xn + rr_ * hn));
        const float nn  = 1.f - 2.f * __builtin_amdgcn_rcpf(1.f + e2);
        hfr[dt][r] = (1.f - zz) * nn + zz * hfr[dt][r];
      }
    }

    // pack h -> next step's B-frags (pure registers; hi + lo split)
    if (ts < WS_ - 1) {
#pragma unroll
      for (int kt = 0; kt < 2; ++kt) {
        short8 hi8, lo8;
#pragma unroll
        for (int i = 0; i < 8; ++i) {
          const float hv = (i < 4) ? hfr[kt][i] : hfr[kt + 2][i - 4];
          const unsigned short hb16 = f2bf(hv);
          hi8[i] = (short)hb16;
          lo8[i] = (short)f2bf(hv - bf2f(hb16));
        }
        bh[kt] = hi8; bl[kt] = lo8;
      }
    }
  }

  // ---- write final hidden (un-permute dims) ----
  float* op = out + (((size_t)b * 24 + (GH_ + gset * 4 + vh)) * L_ + l0 + seqB + c) * DK_;
#pragma unroll
  for (int dt = 0; dt < 4; ++dt)
#pragma unroll
    for (int r = 0; r < 4; ++r) {
      const int dact = ((dt & 1) << 5) + (lg << 3) + ((dt >> 1) << 2) + r;
      op[dact] = hfr[dt][r];
    }
}

extern "C" void kernel_launch(void* const* d_in, const int* in_sizes, int n_in,
                              void* d_out, int out_size, void* d_ws, size_t ws_size,
                              hipStream_t stream) {
  (void)in_sizes; (void)n_in; (void)out_size;
  const float* q   = (const float*)d_in[0];
  const float* k   = (const float*)d_in[1];
  const float* v   = (const float*)d_in[2];
  const int*   msk = (const int*)d_in[3];
  const float* wih = (const float*)d_in[4];
  const float* whh = (const float*)d_in[5];
  const float* bih = (const float*)d_in[6];
  const float* bhh = (const float*)d_in[7];
  float* out = (float*)d_out;

  const int use_bits = (ws_size >= (size_t)MB_WORDS * 8) ? 1 : 0;
  unsigned long long* mb = (unsigned long long*)d_ws;

  (void)hipFuncSetAttribute((const void*)gru_kernel,
                            hipFuncAttributeMaxDynamicSharedMemorySize, GRU_LDS_BYTES);

  if (use_bits)
    maskpack_kernel<<<dim3(MB_WORDS / 256), dim3(256), 0, stream>>>(msk, mb);
  attn_kernel<<<dim3(L_ / 64, GH_, B_), dim3(256), ATTN_LDS_BYTES, stream>>>(
      q, k, v, msk, mb, use_bits, out);
  gru_kernel<<<dim3(L_ / 128, 16, B_), dim3(512), GRU_LDS_BYTES, stream>>>(
      v, wih, whh, bih, bhh, out);
}

// Round 10
// 346.502 us; speedup vs baseline: 1.2460x; 1.2460x over previous
//
#include <hip/hip_runtime.h>

// Problem constants
#define B_  4
#define H_  12
#define L_  1024
#define DK_ 64
#define GH_ 8      // global attention heads
#define WS_ 9      // gru window steps (INIT_VAL+1)

// attention LDS: sK [64][64]bf16 swz + sVT [64][64]bf16 swz + sP 4 waves x [16][64]bf16
#define ATTN_LDS_BYTES (3 * 64 * 64 * 2)   // 24,576
// GRU LDS: W_hh bf16 [192][64] swz (24576) + XGP bf16 [136 pos][192 j] stride 392B (53312)
//        + b_ih f32 [192] (768) + b_hh f32 [192] (768)  -> 79,424  (<80K: 2 blocks/CU)
#define GRU_W_OFF    0
#define GRU_XGP_OFF  24576
#define GRU_BIH_OFF  77888
#define GRU_BHH_OFF  78656
#define GRU_LDS_BYTES 79424
#define XGP_STRIDE   392   // bytes per pos-row (192 bf16 + 4B pad)

#define MB_WORDS (B_ * L_ * 16)            // 65,536 u64 words = 512 KB

typedef __attribute__((ext_vector_type(8))) short short8;
typedef __attribute__((ext_vector_type(4))) float f32x4;

#define MFMA_BF16(a, b, c) __builtin_amdgcn_mfma_f32_16x16x32_bf16((a), (b), (c), 0, 0, 0)

__device__ __forceinline__ unsigned short f2bf(float f) {  // f32 -> bf16 bits, RNE
  unsigned int u = __builtin_bit_cast(unsigned int, f);
  u += 0x7fffu + ((u >> 16) & 1u);
  return (unsigned short)(u >> 16);
}
__device__ __forceinline__ float bf2f(unsigned short s) {  // bf16 bits -> f32 (exact)
  return __builtin_bit_cast(float, ((unsigned int)s) << 16);
}
__device__ __forceinline__ short8 pack8(const float4 a, const float4 b) {
  short8 r;
  r[0] = (short)f2bf(a.x); r[1] = (short)f2bf(a.y);
  r[2] = (short)f2bf(a.z); r[3] = (short)f2bf(a.w);
  r[4] = (short)f2bf(b.x); r[5] = (short)f2bf(b.y);
  r[6] = (short)f2bf(b.z); r[7] = (short)f2bf(b.w);
  return r;
}
__device__ __forceinline__ uint4 packrow16(const float4 a, const float4 b) {
  uint4 r;
  r.x = (unsigned)f2bf(a.x) | ((unsigned)f2bf(a.y) << 16);
  r.y = (unsigned)f2bf(a.z) | ((unsigned)f2bf(a.w) << 16);
  r.z = (unsigned)f2bf(b.x) | ((unsigned)f2bf(b.y) << 16);
  r.w = (unsigned)f2bf(b.z) | ((unsigned)f2bf(b.w) << 16);
  return r;
}
// extract bf16 #r (compile-time r, 0..3) of a uint2 as f32
__device__ __forceinline__ float bfget(const uint2 u, const int r) {
  const unsigned d = (r & 2) ? u.y : u.x;
  return (r & 1) ? __builtin_bit_cast(float, d & 0xffff0000u)
                 : __builtin_bit_cast(float, d << 16);
}
// gate-row permutation: within one 64-row gate block, permuted row rho=(dt,m)
// holds actual row pi = ((dt&1)<<5) + ((m>>2)<<3) + ((dt>>1)<<2) + (m&3).
// Chosen so the GRU recurrence's produced h-dims per lane == the next step's
// B-fragment dims per lane (h hand-off is pure in-register; no LDS/shuffle).
__device__ __forceinline__ int pi_row(const int dt, const int m) {
  return ((dt & 1) << 5) + ((m >> 2) << 3) + ((dt >> 1) << 2) + (m & 3);
}

// ---------------- mask bit-pack: int32 [B][L][L] -> u64 bits [B*L][16] -----
__global__ __launch_bounds__(256) void maskpack_kernel(
    const int* __restrict__ mask, unsigned long long* __restrict__ mb)
{
  const int idx = blockIdx.x * 256 + threadIdx.x;   // word id, 0..65535
  const int* src = mask + (size_t)idx * 64;
  unsigned long long bits = 0ull;
#pragma unroll
  for (int i = 0; i < 16; ++i) {
    const int4 m4 = *(const int4*)(src + i * 4);
    if (m4.x) bits |= 1ull << (i * 4 + 0);
    if (m4.y) bits |= 1ull << (i * 4 + 1);
    if (m4.z) bits |= 1ull << (i * 4 + 2);
    if (m4.w) bits |= 1ull << (i * 4 + 3);
  }
  mb[idx] = bits;
}

// ---------------- Global attention (heads 0..7), bf16 MFMA flash -----------
// grid (L/64, 8, B), block 256 (4 waves). Raw s_barrier + explicit lgkmcnt(0)
// so the 1-deep K/V/mask register prefetch stays in flight across barriers.
__global__ __launch_bounds__(256) void attn_kernel(
    const float* __restrict__ q, const float* __restrict__ k,
    const float* __restrict__ v, const int* __restrict__ mask,
    const unsigned long long* __restrict__ mb, const int use_bits,
    float* __restrict__ out)
{
  extern __shared__ char smc[];
  char* sK  = smc;            // [64][64] bf16, swizzled rows (128B)
  char* sVT = smc + 8192;     // [64][64] bf16: VT[d][kcol], swizzled rows
  char* sP  = smc + 16384;    // wave w: [16][64] bf16 at +2048*w

  const int tid = threadIdx.x;
  const int q0 = blockIdx.x * 64;
  const int h  = blockIdx.y;
  const int b  = blockIdx.z;

  const int w  = tid >> 6;
  const int ln = tid & 63;
  const int lg = ln >> 4;        // lane group 0..3
  const int c  = ln & 15;        // lane col 0..15

  const size_t hbase = ((size_t)b * H_ + h) * L_ * DK_;
  const float* kp = k + hbase;
  const float* vp = v + hbase;
  const int*   mp = mask + (size_t)b * L_ * L_;
  const unsigned long long* mbp = mb + (size_t)b * L_ * 16;

  // Q A-fragments in registers: rows q0 + w*16 + c, d = kt*32 + lg*8 + i
  short8 qa[2];
  {
    const float* qrow = q + hbase + (size_t)(q0 + w * 16 + c) * DK_ + lg * 8;
#pragma unroll
    for (int kt = 0; kt < 2; ++kt) {
      const float4 f0 = *(const float4*)(qrow + kt * 32);
      const float4 f1 = *(const float4*)(qrow + kt * 32 + 4);
      qa[kt] = pack8(f0, f1);
    }
  }

  char* sPw = sP + w * 2048;

  f32x4 o_[4];
#pragma unroll
  for (int nt = 0; nt < 4; ++nt) { o_[nt][0] = 0.f; o_[nt][1] = 0.f; o_[nt][2] = 0.f; o_[nt][3] = 0.f; }
  float mrun[4], lrun[4];
#pragma unroll
  for (int r = 0; r < 4; ++r) { mrun[r] = -1e30f; lrun[r] = 0.f; }

  // staging roles: K: row rr, 16-col chunk c16.  V: row-pair r2, 8-col chunk j0v.
  const int rr  = tid >> 2;
  const int c16 = (tid & 3) << 4;
  const int r2  = (tid & 31) << 1;
  const int j0v = (tid >> 5) << 3;

  // ---- prologue: prefetch tile 0 into registers ----
  float4 kreg[4], vreg[4];
  unsigned long long mreg[4];
  {
    const float* ksrc = kp + (size_t)rr * DK_ + c16;
    kreg[0] = *(const float4*)(ksrc);      kreg[1] = *(const float4*)(ksrc + 4);
    kreg[2] = *(const float4*)(ksrc + 8);  kreg[3] = *(const float4*)(ksrc + 12);
    const float* vsrc = vp + (size_t)r2 * DK_ + j0v;
    vreg[0] = *(const float4*)(vsrc);       vreg[1] = *(const float4*)(vsrc + 4);
    vreg[2] = *(const float4*)(vsrc + 64);  vreg[3] = *(const float4*)(vsrc + 68);
    if (use_bits) {
#pragma unroll
      for (int r = 0; r < 4; ++r)
        mreg[r] = mbp[(size_t)(q0 + w * 16 + lg * 4 + r) * 16 + 0];
    }
  }

  for (int kt0 = 0; kt0 < 16; ++kt0) {
    // ---- write staged tile (registers) to LDS, swizzled ----
    {
      const int kb = rr * 128 + c16 * 2;
      const int sw = (rr & 7) << 4;
      *(uint4*)(sK + ((kb) ^ sw))      = packrow16(kreg[0], kreg[1]);
      *(uint4*)(sK + ((kb + 16) ^ sw)) = packrow16(kreg[2], kreg[3]);
      const float va_[8] = {vreg[0].x, vreg[0].y, vreg[0].z, vreg[0].w,
                            vreg[1].x, vreg[1].y, vreg[1].z, vreg[1].w};
      const float vb_[8] = {vreg[2].x, vreg[2].y, vreg[2].z, vreg[2].w,
                            vreg[3].x, vreg[3].y, vreg[3].z, vreg[3].w};
#pragma unroll
      for (int j = 0; j < 8; ++j) {
        const int d = j0v + j;
        const unsigned u32v = (unsigned)f2bf(va_[j]) | ((unsigned)f2bf(vb_[j]) << 16);
        *(unsigned*)(sVT + ((d * 128 + r2 * 2) ^ ((d & 7) << 4))) = u32v;
      }
    }
    // writes visible to all waves; do NOT drain vmcnt (prefetch stays in flight)
    asm volatile("s_waitcnt lgkmcnt(0)" ::: "memory");
    __builtin_amdgcn_s_barrier();

    // capture this tile's mask words, then issue next tile's loads
    unsigned long long mcur[4];
#pragma unroll
    for (int r = 0; r < 4; ++r) mcur[r] = mreg[r];
    {
      const int ktn = (kt0 + 1) & 15;
      const float* ksrc = kp + (size_t)(ktn * 64 + rr) * DK_ + c16;
      kreg[0] = *(const float4*)(ksrc);      kreg[1] = *(const float4*)(ksrc + 4);
      kreg[2] = *(const float4*)(ksrc + 8);  kreg[3] = *(const float4*)(ksrc + 12);
      const float* vsrc = vp + (size_t)(ktn * 64 + r2) * DK_ + j0v;
      vreg[0] = *(const float4*)(vsrc);       vreg[1] = *(const float4*)(vsrc + 4);
      vreg[2] = *(const float4*)(vsrc + 64);  vreg[3] = *(const float4*)(vsrc + 68);
      if (use_bits) {
#pragma unroll
        for (int r = 0; r < 4; ++r)
          mreg[r] = mbp[(size_t)(q0 + w * 16 + lg * 4 + r) * 16 + ktn];
      }
    }

    // ---- S = Q K^T : 4 N-tiles x 2 K-chunks ----
    f32x4 acc[4];
#pragma unroll
    for (int nt = 0; nt < 4; ++nt) {
      acc[nt][0] = 0.f; acc[nt][1] = 0.f; acc[nt][2] = 0.f; acc[nt][3] = 0.f;
#pragma unroll
      for (int kt = 0; kt < 2; ++kt) {
        const int off = (((nt * 16 + c) * 128 + kt * 64 + lg * 16) ^ ((c & 7) << 4));
        const short8 bk = __builtin_bit_cast(short8, *(const uint4*)(sK + off));
        acc[nt] = MFMA_BF16(qa[kt], bk, acc[nt]);
      }
    }

    // ---- mask + online softmax (rows lg*4+r; 16 c-lanes share a row) ----
#pragma unroll
    for (int r = 0; r < 4; ++r) {
      bool k0_, k1_, k2_, k3_;
      if (use_bits) {
        const unsigned long long mword = mcur[r];
        k0_ = (mword >> (c)) & 1ull;
        k1_ = (mword >> (16 + c)) & 1ull;
        k2_ = (mword >> (32 + c)) & 1ull;
        k3_ = (mword >> (48 + c)) & 1ull;
      } else {
        const int qr = q0 + w * 16 + lg * 4 + r;
        const int* mrow = mp + (size_t)qr * L_ + kt0 * 64 + c;
        k0_ = mrow[0] != 0; k1_ = mrow[16] != 0; k2_ = mrow[32] != 0; k3_ = mrow[48] != 0;
      }
      const float s0_ = k0_ ? acc[0][r] * 0.125f : -1e12f;
      const float s1_ = k1_ ? acc[1][r] * 0.125f : -1e12f;
      const float s2_ = k2_ ? acc[2][r] * 0.125f : -1e12f;
      const float s3_ = k3_ ? acc[3][r] * 0.125f : -1e12f;
      float mt = fmaxf(fmaxf(s0_, s1_), fmaxf(s2_, s3_));
#pragma unroll
      for (int off = 1; off < 16; off <<= 1) mt = fmaxf(mt, __shfl_xor(mt, off));
      const float mnew = fmaxf(mrun[r], mt);
      const float p0 = __expf(s0_ - mnew);
      const float p1 = __expf(s1_ - mnew);
      const float p2 = __expf(s2_ - mnew);
      const float p3 = __expf(s3_ - mnew);
      float pt = p0 + p1 + p2 + p3;
#pragma unroll
      for (int off = 1; off < 16; off <<= 1) pt += __shfl_xor(pt, off);
      const float scale = __expf(mrun[r] - mnew);
      mrun[r] = mnew;
      lrun[r] = lrun[r] * scale + pt;
      o_[0][r] *= scale; o_[1][r] *= scale; o_[2][r] *= scale; o_[3][r] *= scale;
      const int prow = lg * 4 + r;
      const int pb = prow * 128;
      const int psw = (prow & 7) << 4;
      *(unsigned short*)(sPw + ((pb + (c * 2)) ^ psw))       = f2bf(p0);
      *(unsigned short*)(sPw + ((pb + (16 + c) * 2) ^ psw))  = f2bf(p1);
      *(unsigned short*)(sPw + ((pb + (32 + c) * 2) ^ psw))  = f2bf(p2);
      *(unsigned short*)(sPw + ((pb + (48 + c) * 2) ^ psw))  = f2bf(p3);
    }

    // ---- O += P V  (A = P from wave-private LDS, B = V^T) ----
#pragma unroll
    for (int kt = 0; kt < 2; ++kt) {
      const int aoff = ((c * 128 + kt * 64 + lg * 16) ^ ((c & 7) << 4));
      const short8 pa = __builtin_bit_cast(short8, *(const uint4*)(sPw + aoff));
#pragma unroll
      for (int nt = 0; nt < 4; ++nt) {
        const int boff = (((nt * 16 + c) * 128 + kt * 64 + lg * 16) ^ ((c & 7) << 4));
        const short8 bv = __builtin_bit_cast(short8, *(const uint4*)(sVT + boff));
        o_[nt] = MFMA_BF16(pa, bv, o_[nt]);
      }
    }
    // drain LDS ops (reads consumed; keeps vmcnt untouched), then barrier
    asm volatile("s_waitcnt lgkmcnt(0)" ::: "memory");
    __builtin_amdgcn_s_barrier();
  }

  // ---- finalize: divide by l, store f32 ----
  float* op = out + (((size_t)b * 24 + h) * L_ + q0 + w * 16) * DK_;
#pragma unroll
  for (int r = 0; r < 4; ++r) {
    const float inv = 1.f / lrun[r];
#pragma unroll
    for (int nt = 0; nt < 4; ++nt)
      op[(size_t)(lg * 4 + r) * DK_ + nt * 16 + c] = o_[nt][r] * inv;
  }
}

// ---------------- GRU (heads 8..23), bf16 MFMA, permuted-gate layout --------
// grid (L/128, 16, B), block 512 (8 waves), 79.4KB LDS -> 2 blocks/CU.
// SWAPPED MFMA: A = W (j-tiles), B = h/v (pos); lane owns one sequence.
// Round-10 fix: PER-DT gate processing in a runtime ts-loop. Round 9's fully
// unrolled loop kept acc[12]+xg[12]+frags live (~120 regs) against the
// 128-reg cap of __launch_bounds__(512,4) -> 711 MB/dispatch scratch spill
// (FETCH 428MB). Per-dt needs only 3 acc f32x4 + 3 xg live at once (~80 regs
// peak). bh/bl zero-init replaces the ts==0 special case.
__global__ __launch_bounds__(512, 4) void gru_kernel(
    const float* __restrict__ value, const float* __restrict__ wih_g,
    const float* __restrict__ whh_g, const float* __restrict__ bih_g,
    const float* __restrict__ bhh_g, float* __restrict__ out)
{
  extern __shared__ char smc[];
  char*  sW   = smc + GRU_W_OFF;       // W_hh bf16 swz [192][64], permuted rows
  char*  sXGP = smc + GRU_XGP_OFF;     // bf16 [136 pos][192 j], stride 392B
  float* sBih = (float*)(smc + GRU_BIH_OFF);  // [192]
  float* sBhh = (float*)(smc + GRU_BHH_OFF);  // [192]

  const int tid  = threadIdx.x;
  const int l0   = blockIdx.x * 128;
  const int gset = blockIdx.y >> 2;
  const int vh   = blockIdx.y & 3;
  const int b    = blockIdx.z;

  const float* vp   = value + (((size_t)b * H_ + GH_ + vh) * L_) * DK_;
  const float* wih  = wih_g + (size_t)gset * 192 * DK_;
  const float* whh  = whh_g + (size_t)gset * 192 * DK_;
  const float* bihp = bih_g + gset * 192;
  const float* bhhp = bhh_g + gset * 192;

  if (tid < 192) { sBih[tid] = bihp[tid]; sBhh[tid] = bhhp[tid]; }

  // stage W_hh -> bf16 swizzled LDS, rows in PERMUTED order
  for (int cid = tid; cid < 1536; cid += 512) {   // 192 rows * 8 chunks(16B)
    const int row = cid >> 3, ch = cid & 7;       // row = permuted-space index
    const int g = row >> 6, dt = (row >> 4) & 3, m = row & 15;
    const int arow = g * 64 + pi_row(dt, m);
    const float* wp = whh + (size_t)arow * 64 + ch * 8;
    const float4 w0 = *(const float4*)wp;
    const float4 w1 = *(const float4*)(wp + 4);
    *(uint4*)(sW + ((row * 128 + ch * 16) ^ ((row & 7) << 4))) = packrow16(w0, w1);
  }
  __syncthreads();

  const int w  = tid >> 6;
  const int ln = tid & 63;
  const int lg = ln >> 4;
  const int c  = ln & 15;

  // ---- phase 1 (swapped): XGP[pos][j] = W_ih[aj]·v[pos] + b_ih (+ b_hh r,z) --
  for (int t = w; t < 108; t += 8) {
    const int jt = t % 12, pt = t / 12;
    const int g = jt >> 2, dt = jt & 3;
    const int aj = g * 64 + pi_row(dt, c);
    const float* wb = wih + (size_t)aj * 64 + lg * 8;
    const short8 aA = pack8(*(const float4*)(wb),      *(const float4*)(wb + 4));
    const short8 aB = pack8(*(const float4*)(wb + 32), *(const float4*)(wb + 36));
    const int pos = pt * 16 + c;
    const int gp  = l0 + pos;
    const bool valid = gp < L_;
    float4 z4; z4.x = 0.f; z4.y = 0.f; z4.z = 0.f; z4.w = 0.f;
    const float* va = vp + (size_t)gp * 64 + lg * 8;
    const short8 bA = pack8(valid ? *(const float4*)(va)      : z4,
                            valid ? *(const float4*)(va + 4)  : z4);
    const short8 bB = pack8(valid ? *(const float4*)(va + 32) : z4,
                            valid ? *(const float4*)(va + 36) : z4);
    f32x4 acc = {0.f, 0.f, 0.f, 0.f};
    acc = MFMA_BF16(aA, bA, acc);
    acc = MFMA_BF16(aB, bB, acc);
    const int jb = g * 64 + ((dt & 1) << 5) + (lg << 3) + ((dt >> 1) << 2);
    const f32x4 bi = *(const f32x4*)(sBih + jb);
    const f32x4 bh4 = *(const f32x4*)(sBhh + jb);
    const float foldh = (g < 2) ? 1.f : 0.f;   // fold b_hh only for r,z gates
    if (pos < 136) {
      uint2 pk;
      pk.x = (unsigned)f2bf(acc[0] + bi[0] + foldh * bh4[0]) |
             ((unsigned)f2bf(acc[1] + bi[1] + foldh * bh4[1]) << 16);
      pk.y = (unsigned)f2bf(acc[2] + bi[2] + foldh * bh4[2]) |
             ((unsigned)f2bf(acc[3] + bi[3] + foldh * bh4[3]) << 16);
      *(uint2*)(sXGP + pos * XGP_STRIDE + jt * 32 + lg * 8) = pk;
    }
  }
  __syncthreads();

  // ---- recurrence: 9 steps, no LDS writes / shuffles / barriers ----
  const int seqB = w * 16;
  const int xrow0 = seqB + c;            // this lane's sequence (local pos)

  // b_hh_n for this lane's n-gate dims (actual rows 128 + dact), loop-invariant
  f32x4 bhn[4];
#pragma unroll
  for (int dt = 0; dt < 4; ++dt)
    bhn[dt] = *(const f32x4*)(sBhh + 128 + ((dt & 1) << 5) + (lg << 3) + ((dt >> 1) << 2));

  float hfr[4][4];                       // [dt][r]: actual dim pi_row(dt, lg*4+r)
  short8 bh[2], bl[2];                   // h B-frags (hi/lo), zero-init (h0 = 0)
#pragma unroll
  for (int dt = 0; dt < 4; ++dt)
#pragma unroll
    for (int r = 0; r < 4; ++r) hfr[dt][r] = 0.f;
#pragma unroll
  for (int kt = 0; kt < 2; ++kt) {
#pragma unroll
    for (int i = 0; i < 8; ++i) { bh[kt][i] = 0; bl[kt][i] = 0; }
  }

  const int swz = (c & 7) << 4;

  for (int ts = 0; ts < WS_; ++ts) {
    const int xbase = (xrow0 + ts) * XGP_STRIDE + lg * 8;

#pragma unroll
    for (int dt = 0; dt < 4; ++dt) {
      // this dt's xg (r,z,n) — 3 b64 reads
      const uint2 xgr = *(const uint2*)(sXGP + xbase + dt * 32);
      const uint2 xgz = *(const uint2*)(sXGP + xbase + (4 + dt) * 32);
      const uint2 xgn = *(const uint2*)(sXGP + xbase + (8 + dt) * 32);

      f32x4 ar = {0.f, 0.f, 0.f, 0.f};
      f32x4 az = {0.f, 0.f, 0.f, 0.f};
      f32x4 an = {0.f, 0.f, 0.f, 0.f};
#pragma unroll
      for (int kt = 0; kt < 2; ++kt) {
        const int base = kt * 64 + lg * 16;
        const short8 wr = __builtin_bit_cast(short8,
            *(const uint4*)(sW + ((((dt)     * 16 + c) * 128 + base) ^ swz)));
        const short8 wz = __builtin_bit_cast(short8,
            *(const uint4*)(sW + ((((4 + dt) * 16 + c) * 128 + base) ^ swz)));
        const short8 wn = __builtin_bit_cast(short8,
            *(const uint4*)(sW + ((((8 + dt) * 16 + c) * 128 + base) ^ swz)));
        ar = MFMA_BF16(wr, bh[kt], ar); ar = MFMA_BF16(wr, bl[kt], ar);
        az = MFMA_BF16(wz, bh[kt], az); az = MFMA_BF16(wz, bl[kt], az);
        an = MFMA_BF16(wn, bh[kt], an); an = MFMA_BF16(wn, bl[kt], an);
      }

      // gates + h update for this dt (4 dims)
#pragma unroll
      for (int r = 0; r < 4; ++r) {
        const float xr = bfget(xgr, r);
        const float xz = bfget(xgz, r);
        const float xn = bfget(xgn, r);
        const float rr_ = __builtin_amdgcn_rcpf(1.f + __expf(-(xr + ar[r])));
        const float zz  = __builtin_amdgcn_rcpf(1.f + __expf(-(xz + az[r])));
        const float hn  = an[r] + bhn[dt][r];     // b_hh_n NOT folded
        const float e2  = __expf(2.f * (xn + rr_ * hn));
        const float nn  = 1.f - 2.f * __builtin_amdgcn_rcpf(1.f + e2);
        hfr[dt][r] = (1.f - zz) * nn + zz * hfr[dt][r];
      }
    }

    // pack h -> next step's B-frags (pure registers; hi + lo split)
#pragma unroll
    for (int kt = 0; kt < 2; ++kt) {
      short8 hi8, lo8;
#pragma unroll
      for (int i = 0; i < 8; ++i) {
        const float hv = (i < 4) ? hfr[kt][i] : hfr[kt + 2][i - 4];
        const unsigned short hb16 = f2bf(hv);
        hi8[i] = (short)hb16;
        lo8[i] = (short)f2bf(hv - bf2f(hb16));
      }
      bh[kt] = hi8; bl[kt] = lo8;
    }
  }

  // ---- write final hidden (un-permute dims) ----
  float* op = out + (((size_t)b * 24 + (GH_ + gset * 4 + vh)) * L_ + l0 + seqB + c) * DK_;
#pragma unroll
  for (int dt = 0; dt < 4; ++dt)
#pragma unroll
    for (int r = 0; r < 4; ++r) {
      const int dact = ((dt & 1) << 5) + (lg << 3) + ((dt >> 1) << 2) + r;
      op[dact] = hfr[dt][r];
    }
}

extern "C" void kernel_launch(void* const* d_in, const int* in_sizes, int n_in,
                              void* d_out, int out_size, void* d_ws, size_t ws_size,
                              hipStream_t stream) {
  (void)in_sizes; (void)n_in; (void)out_size;
  const float* q   = (const float*)d_in[0];
  const float* k   = (const float*)d_in[1];
  const float* v   = (const float*)d_in[2];
  const int*   msk = (const int*)d_in[3];
  const float* wih = (const float*)d_in[4];
  const float* whh = (const float*)d_in[5];
  const float* bih = (const float*)d_in[6];
  const float* bhh = (const float*)d_in[7];
  float* out = (float*)d_out;

  const int use_bits = (ws_size >= (size_t)MB_WORDS * 8) ? 1 : 0;
  unsigned long long* mb = (unsigned long long*)d_ws;

  (void)hipFuncSetAttribute((const void*)gru_kernel,
                            hipFuncAttributeMaxDynamicSharedMemorySize, GRU_LDS_BYTES);

  if (use_bits)
    maskpack_kernel<<<dim3(MB_WORDS / 256), dim3(256), 0, stream>>>(msk, mb);
  attn_kernel<<<dim3(L_ / 64, GH_, B_), dim3(256), ATTN_LDS_BYTES, stream>>>(
      q, k, v, msk, mb, use_bits, out);
  gru_kernel<<<dim3(L_ / 128, 16, B_), dim3(512), GRU_LDS_BYTES, stream>>>(
      v, wih, whh, bih, bhh, out);
}

// Round 11
// 309.924 us; speedup vs baseline: 1.3931x; 1.1180x over previous
//
#include <hip/hip_runtime.h>

// Problem constants
#define B_  4
#define H_  12
#define L_  1024
#define DK_ 64
#define GH_ 8      // global attention heads
#define WS_ 9      // gru window steps (INIT_VAL+1)

// attention LDS: sK [64][64]bf16 swz + sVT [64][64]bf16 swz + sP 4 waves x [16][64]bf16
#define ATTN_LDS_BYTES (3 * 64 * 64 * 2)   // 24,576
// GRU LDS (64-seq blocks): W_hh bf16 [192][64] swz (24576)
//   + XGP bf16 [72 pos][192 j] stride 392B (28224) + b_ih/b_hh f32 (1536) = 54,336
// -> 2 blocks/CU by LDS; __launch_bounds__(256,2) caps regs at 256 (no spill).
#define GRU_W_OFF    0
#define GRU_XGP_OFF  24576
#define GRU_BIH_OFF  52800
#define GRU_BHH_OFF  53568
#define GRU_LDS_BYTES 54336
#define XGP_STRIDE   392   // bytes per pos-row (192 bf16 + 4B pad)

#define MB_WORDS (B_ * L_ * 16)            // 65,536 u64 words = 512 KB

typedef __attribute__((ext_vector_type(8))) short short8;
typedef __attribute__((ext_vector_type(4))) float f32x4;

#define MFMA_BF16(a, b, c) __builtin_amdgcn_mfma_f32_16x16x32_bf16((a), (b), (c), 0, 0, 0)

__device__ __forceinline__ unsigned short f2bf(float f) {  // f32 -> bf16 bits, RNE
  unsigned int u = __builtin_bit_cast(unsigned int, f);
  u += 0x7fffu + ((u >> 16) & 1u);
  return (unsigned short)(u >> 16);
}
__device__ __forceinline__ float bf2f(unsigned short s) {  // bf16 bits -> f32 (exact)
  return __builtin_bit_cast(float, ((unsigned int)s) << 16);
}
__device__ __forceinline__ short8 pack8(const float4 a, const float4 b) {
  short8 r;
  r[0] = (short)f2bf(a.x); r[1] = (short)f2bf(a.y);
  r[2] = (short)f2bf(a.z); r[3] = (short)f2bf(a.w);
  r[4] = (short)f2bf(b.x); r[5] = (short)f2bf(b.y);
  r[6] = (short)f2bf(b.z); r[7] = (short)f2bf(b.w);
  return r;
}
__device__ __forceinline__ uint4 packrow16(const float4 a, const float4 b) {
  uint4 r;
  r.x = (unsigned)f2bf(a.x) | ((unsigned)f2bf(a.y) << 16);
  r.y = (unsigned)f2bf(a.z) | ((unsigned)f2bf(a.w) << 16);
  r.z = (unsigned)f2bf(b.x) | ((unsigned)f2bf(b.y) << 16);
  r.w = (unsigned)f2bf(b.z) | ((unsigned)f2bf(b.w) << 16);
  return r;
}
// extract bf16 #r (compile-time r, 0..3) of a uint2 as f32
__device__ __forceinline__ float bfget(const uint2 u, const int r) {
  const unsigned d = (r & 2) ? u.y : u.x;
  return (r & 1) ? __builtin_bit_cast(float, d & 0xffff0000u)
                 : __builtin_bit_cast(float, d << 16);
}
// gate-row permutation: within one 64-row gate block, permuted row rho=(dt,m)
// holds actual row pi = ((dt&1)<<5) + ((m>>2)<<3) + ((dt>>1)<<2) + (m&3).
// Chosen so the GRU recurrence's produced h-dims per lane == the next step's
// B-fragment dims per lane (h hand-off is pure in-register; no LDS/shuffle).
__device__ __forceinline__ int pi_row(const int dt, const int m) {
  return ((dt & 1) << 5) + ((m >> 2) << 3) + ((dt >> 1) << 2) + (m & 3);
}

// ---------------- mask bit-pack: int32 [B][L][L] -> u64 bits [B*L][16] -----
__global__ __launch_bounds__(256) void maskpack_kernel(
    const int* __restrict__ mask, unsigned long long* __restrict__ mb)
{
  const int idx = blockIdx.x * 256 + threadIdx.x;   // word id, 0..65535
  const int* src = mask + (size_t)idx * 64;
  unsigned long long bits = 0ull;
#pragma unroll
  for (int i = 0; i < 16; ++i) {
    const int4 m4 = *(const int4*)(src + i * 4);
    if (m4.x) bits |= 1ull << (i * 4 + 0);
    if (m4.y) bits |= 1ull << (i * 4 + 1);
    if (m4.z) bits |= 1ull << (i * 4 + 2);
    if (m4.w) bits |= 1ull << (i * 4 + 3);
  }
  mb[idx] = bits;
}

// ---------------- Global attention (heads 0..7), bf16 MFMA flash -----------
// grid (L/64, 8, B), block 256 (4 waves). Raw s_barrier + explicit lgkmcnt(0)
// so the 1-deep K/V/mask register prefetch stays in flight across barriers.
__global__ __launch_bounds__(256) void attn_kernel(
    const float* __restrict__ q, const float* __restrict__ k,
    const float* __restrict__ v, const int* __restrict__ mask,
    const unsigned long long* __restrict__ mb, const int use_bits,
    float* __restrict__ out)
{
  extern __shared__ char smc[];
  char* sK  = smc;            // [64][64] bf16, swizzled rows (128B)
  char* sVT = smc + 8192;     // [64][64] bf16: VT[d][kcol], swizzled rows
  char* sP  = smc + 16384;    // wave w: [16][64] bf16 at +2048*w

  const int tid = threadIdx.x;
  const int q0 = blockIdx.x * 64;
  const int h  = blockIdx.y;
  const int b  = blockIdx.z;

  const int w  = tid >> 6;
  const int ln = tid & 63;
  const int lg = ln >> 4;        // lane group 0..3
  const int c  = ln & 15;        // lane col 0..15

  const size_t hbase = ((size_t)b * H_ + h) * L_ * DK_;
  const float* kp = k + hbase;
  const float* vp = v + hbase;
  const int*   mp = mask + (size_t)b * L_ * L_;
  const unsigned long long* mbp = mb + (size_t)b * L_ * 16;

  // Q A-fragments in registers: rows q0 + w*16 + c, d = kt*32 + lg*8 + i
  short8 qa[2];
  {
    const float* qrow = q + hbase + (size_t)(q0 + w * 16 + c) * DK_ + lg * 8;
#pragma unroll
    for (int kt = 0; kt < 2; ++kt) {
      const float4 f0 = *(const float4*)(qrow + kt * 32);
      const float4 f1 = *(const float4*)(qrow + kt * 32 + 4);
      qa[kt] = pack8(f0, f1);
    }
  }

  char* sPw = sP + w * 2048;

  f32x4 o_[4];
#pragma unroll
  for (int nt = 0; nt < 4; ++nt) { o_[nt][0] = 0.f; o_[nt][1] = 0.f; o_[nt][2] = 0.f; o_[nt][3] = 0.f; }
  float mrun[4], lrun[4];
#pragma unroll
  for (int r = 0; r < 4; ++r) { mrun[r] = -1e30f; lrun[r] = 0.f; }

  // staging roles: K: row rr, 16-col chunk c16.  V: row-pair r2, 8-col chunk j0v.
  const int rr  = tid >> 2;
  const int c16 = (tid & 3) << 4;
  const int r2  = (tid & 31) << 1;
  const int j0v = (tid >> 5) << 3;

  // ---- prologue: prefetch tile 0 into registers ----
  float4 kreg[4], vreg[4];
  unsigned long long mreg[4];
  {
    const float* ksrc = kp + (size_t)rr * DK_ + c16;
    kreg[0] = *(const float4*)(ksrc);      kreg[1] = *(const float4*)(ksrc + 4);
    kreg[2] = *(const float4*)(ksrc + 8);  kreg[3] = *(const float4*)(ksrc + 12);
    const float* vsrc = vp + (size_t)r2 * DK_ + j0v;
    vreg[0] = *(const float4*)(vsrc);       vreg[1] = *(const float4*)(vsrc + 4);
    vreg[2] = *(const float4*)(vsrc + 64);  vreg[3] = *(const float4*)(vsrc + 68);
    if (use_bits) {
#pragma unroll
      for (int r = 0; r < 4; ++r)
        mreg[r] = mbp[(size_t)(q0 + w * 16 + lg * 4 + r) * 16 + 0];
    }
  }

  for (int kt0 = 0; kt0 < 16; ++kt0) {
    // ---- write staged tile (registers) to LDS, swizzled ----
    {
      const int kb = rr * 128 + c16 * 2;
      const int sw = (rr & 7) << 4;
      *(uint4*)(sK + ((kb) ^ sw))      = packrow16(kreg[0], kreg[1]);
      *(uint4*)(sK + ((kb + 16) ^ sw)) = packrow16(kreg[2], kreg[3]);
      const float va_[8] = {vreg[0].x, vreg[0].y, vreg[0].z, vreg[0].w,
                            vreg[1].x, vreg[1].y, vreg[1].z, vreg[1].w};
      const float vb_[8] = {vreg[2].x, vreg[2].y, vreg[2].z, vreg[2].w,
                            vreg[3].x, vreg[3].y, vreg[3].z, vreg[3].w};
#pragma unroll
      for (int j = 0; j < 8; ++j) {
        const int d = j0v + j;
        const unsigned u32v = (unsigned)f2bf(va_[j]) | ((unsigned)f2bf(vb_[j]) << 16);
        *(unsigned*)(sVT + ((d * 128 + r2 * 2) ^ ((d & 7) << 4))) = u32v;
      }
    }
    // writes visible to all waves; do NOT drain vmcnt (prefetch stays in flight)
    asm volatile("s_waitcnt lgkmcnt(0)" ::: "memory");
    __builtin_amdgcn_s_barrier();

    // capture this tile's mask words, then issue next tile's loads
    unsigned long long mcur[4];
#pragma unroll
    for (int r = 0; r < 4; ++r) mcur[r] = mreg[r];
    {
      const int ktn = (kt0 + 1) & 15;
      const float* ksrc = kp + (size_t)(ktn * 64 + rr) * DK_ + c16;
      kreg[0] = *(const float4*)(ksrc);      kreg[1] = *(const float4*)(ksrc + 4);
      kreg[2] = *(const float4*)(ksrc + 8);  kreg[3] = *(const float4*)(ksrc + 12);
      const float* vsrc = vp + (size_t)(ktn * 64 + r2) * DK_ + j0v;
      vreg[0] = *(const float4*)(vsrc);       vreg[1] = *(const float4*)(vsrc + 4);
      vreg[2] = *(const float4*)(vsrc + 64);  vreg[3] = *(const float4*)(vsrc + 68);
      if (use_bits) {
#pragma unroll
        for (int r = 0; r < 4; ++r)
          mreg[r] = mbp[(size_t)(q0 + w * 16 + lg * 4 + r) * 16 + ktn];
      }
    }

    // ---- S = Q K^T : 4 N-tiles x 2 K-chunks ----
    f32x4 acc[4];
#pragma unroll
    for (int nt = 0; nt < 4; ++nt) {
      acc[nt][0] = 0.f; acc[nt][1] = 0.f; acc[nt][2] = 0.f; acc[nt][3] = 0.f;
#pragma unroll
      for (int kt = 0; kt < 2; ++kt) {
        const int off = (((nt * 16 + c) * 128 + kt * 64 + lg * 16) ^ ((c & 7) << 4));
        const short8 bk = __builtin_bit_cast(short8, *(const uint4*)(sK + off));
        acc[nt] = MFMA_BF16(qa[kt], bk, acc[nt]);
      }
    }

    // ---- mask + online softmax (rows lg*4+r; 16 c-lanes share a row) ----
#pragma unroll
    for (int r = 0; r < 4; ++r) {
      bool k0_, k1_, k2_, k3_;
      if (use_bits) {
        const unsigned long long mword = mcur[r];
        k0_ = (mword >> (c)) & 1ull;
        k1_ = (mword >> (16 + c)) & 1ull;
        k2_ = (mword >> (32 + c)) & 1ull;
        k3_ = (mword >> (48 + c)) & 1ull;
      } else {
        const int qr = q0 + w * 16 + lg * 4 + r;
        const int* mrow = mp + (size_t)qr * L_ + kt0 * 64 + c;
        k0_ = mrow[0] != 0; k1_ = mrow[16] != 0; k2_ = mrow[32] != 0; k3_ = mrow[48] != 0;
      }
      const float s0_ = k0_ ? acc[0][r] * 0.125f : -1e12f;
      const float s1_ = k1_ ? acc[1][r] * 0.125f : -1e12f;
      const float s2_ = k2_ ? acc[2][r] * 0.125f : -1e12f;
      const float s3_ = k3_ ? acc[3][r] * 0.125f : -1e12f;
      float mt = fmaxf(fmaxf(s0_, s1_), fmaxf(s2_, s3_));
#pragma unroll
      for (int off = 1; off < 16; off <<= 1) mt = fmaxf(mt, __shfl_xor(mt, off));
      const float mnew = fmaxf(mrun[r], mt);
      const float p0 = __expf(s0_ - mnew);
      const float p1 = __expf(s1_ - mnew);
      const float p2 = __expf(s2_ - mnew);
      const float p3 = __expf(s3_ - mnew);
      float pt = p0 + p1 + p2 + p3;
#pragma unroll
      for (int off = 1; off < 16; off <<= 1) pt += __shfl_xor(pt, off);
      const float scale = __expf(mrun[r] - mnew);
      mrun[r] = mnew;
      lrun[r] = lrun[r] * scale + pt;
      o_[0][r] *= scale; o_[1][r] *= scale; o_[2][r] *= scale; o_[3][r] *= scale;
      const int prow = lg * 4 + r;
      const int pb = prow * 128;
      const int psw = (prow & 7) << 4;
      *(unsigned short*)(sPw + ((pb + (c * 2)) ^ psw))       = f2bf(p0);
      *(unsigned short*)(sPw + ((pb + (16 + c) * 2) ^ psw))  = f2bf(p1);
      *(unsigned short*)(sPw + ((pb + (32 + c) * 2) ^ psw))  = f2bf(p2);
      *(unsigned short*)(sPw + ((pb + (48 + c) * 2) ^ psw))  = f2bf(p3);
    }

    // ---- O += P V  (A = P from wave-private LDS, B = V^T) ----
#pragma unroll
    for (int kt = 0; kt < 2; ++kt) {
      const int aoff = ((c * 128 + kt * 64 + lg * 16) ^ ((c & 7) << 4));
      const short8 pa = __builtin_bit_cast(short8, *(const uint4*)(sPw + aoff));
#pragma unroll
      for (int nt = 0; nt < 4; ++nt) {
        const int boff = (((nt * 16 + c) * 128 + kt * 64 + lg * 16) ^ ((c & 7) << 4));
        const short8 bv = __builtin_bit_cast(short8, *(const uint4*)(sVT + boff));
        o_[nt] = MFMA_BF16(pa, bv, o_[nt]);
      }
    }
    // drain LDS ops (reads consumed; keeps vmcnt untouched), then barrier
    asm volatile("s_waitcnt lgkmcnt(0)" ::: "memory");
    __builtin_amdgcn_s_barrier();
  }

  // ---- finalize: divide by l, store f32 ----
  float* op = out + (((size_t)b * 24 + h) * L_ + q0 + w * 16) * DK_;
#pragma unroll
  for (int r = 0; r < 4; ++r) {
    const float inv = 1.f / lrun[r];
#pragma unroll
    for (int nt = 0; nt < 4; ++nt)
      op[(size_t)(lg * 4 + r) * DK_ + nt * 16 + c] = o_[nt][r] * inv;
  }
}

// ---------------- GRU (heads 8..23), bf16 MFMA, permuted-gate layout --------
// grid (L/64, 16, B) = 1024 blocks, block 256 (4 waves), 54.3KB LDS ->
// 2 blocks/CU. __launch_bounds__(256,2) -> 256-reg cap: rounds 9/10 spilled
// 200-700MB/dispatch to scratch under the 128-reg cap of (512,4); the live
// set (~190 regs incl. 24 hoisted W-fragments) now fits with zero scratch.
// SWAPPED MFMA: A = W (j-tiles), B = h/v (pos); lane owns one sequence.
// W-fragments are ts-loop-INVARIANT -> hoisted to registers once (96 VGPR),
// removing 24 ds_read_b128/step. Per step: 12 ds_read_b64 (xg) + 48 MFMA +
// gate VALU; no LDS writes / shuffles / barriers in the 9-step loop.
// Bias folding: XGP folds b_ih (all gates) + b_hh (r,z only; additive inside
// sigmoid). b_hh_n kept in regs: n = tanh(xn + r*(h.W_n + b_hh_n)).
__global__ __launch_bounds__(256, 2) void gru_kernel(
    const float* __restrict__ value, const float* __restrict__ wih_g,
    const float* __restrict__ whh_g, const float* __restrict__ bih_g,
    const float* __restrict__ bhh_g, float* __restrict__ out)
{
  extern __shared__ char smc[];
  char*  sW   = smc + GRU_W_OFF;       // W_hh bf16 swz [192][64], permuted rows
  char*  sXGP = smc + GRU_XGP_OFF;     // bf16 [72 pos][192 j], stride 392B
  float* sBih = (float*)(smc + GRU_BIH_OFF);  // [192]
  float* sBhh = (float*)(smc + GRU_BHH_OFF);  // [192]

  const int tid  = threadIdx.x;
  const int l0   = blockIdx.x * 64;
  const int gset = blockIdx.y >> 2;
  const int vh   = blockIdx.y & 3;
  const int b    = blockIdx.z;

  const float* vp   = value + (((size_t)b * H_ + GH_ + vh) * L_) * DK_;
  const float* wih  = wih_g + (size_t)gset * 192 * DK_;
  const float* whh  = whh_g + (size_t)gset * 192 * DK_;
  const float* bihp = bih_g + gset * 192;
  const float* bhhp = bhh_g + gset * 192;

  if (tid < 192) { sBih[tid] = bihp[tid]; sBhh[tid] = bhhp[tid]; }

  // stage W_hh -> bf16 swizzled LDS, rows in PERMUTED order
  for (int cid = tid; cid < 1536; cid += 256) {   // 192 rows * 8 chunks(16B)
    const int row = cid >> 3, ch = cid & 7;       // row = permuted-space index
    const int g = row >> 6, dt = (row >> 4) & 3, m = row & 15;
    const int arow = g * 64 + pi_row(dt, m);
    const float* wp = whh + (size_t)arow * 64 + ch * 8;
    const float4 w0 = *(const float4*)wp;
    const float4 w1 = *(const float4*)(wp + 4);
    *(uint4*)(sW + ((row * 128 + ch * 16) ^ ((row & 7) << 4))) = packrow16(w0, w1);
  }
  __syncthreads();

  const int w  = tid >> 6;
  const int ln = tid & 63;
  const int lg = ln >> 4;
  const int c  = ln & 15;

  // ---- phase 1 (swapped): XGP[pos][j] = W_ih[aj]·v[pos] + b_ih (+ b_hh r,z) --
  // 12 j-tiles x 5 pos-tiles (80 >= 72 positions), wave-strided.
  for (int t = w; t < 60; t += 4) {
    const int jt = t % 12, pt = t / 12;
    const int g = jt >> 2, dt = jt & 3;
    const int aj = g * 64 + pi_row(dt, c);
    const float* wb = wih + (size_t)aj * 64 + lg * 8;
    const short8 aA = pack8(*(const float4*)(wb),      *(const float4*)(wb + 4));
    const short8 aB = pack8(*(const float4*)(wb + 32), *(const float4*)(wb + 36));
    const int pos = pt * 16 + c;
    const int gp  = l0 + pos;
    const bool valid = gp < L_;
    float4 z4; z4.x = 0.f; z4.y = 0.f; z4.z = 0.f; z4.w = 0.f;
    const float* va = vp + (size_t)gp * 64 + lg * 8;
    const short8 bA = pack8(valid ? *(const float4*)(va)      : z4,
                            valid ? *(const float4*)(va + 4)  : z4);
    const short8 bB = pack8(valid ? *(const float4*)(va + 32) : z4,
                            valid ? *(const float4*)(va + 36) : z4);
    f32x4 acc = {0.f, 0.f, 0.f, 0.f};
    acc = MFMA_BF16(aA, bA, acc);
    acc = MFMA_BF16(aB, bB, acc);
    const int jb = g * 64 + ((dt & 1) << 5) + (lg << 3) + ((dt >> 1) << 2);
    const f32x4 bi = *(const f32x4*)(sBih + jb);
    const f32x4 bh4 = *(const f32x4*)(sBhh + jb);
    const float foldh = (g < 2) ? 1.f : 0.f;   // fold b_hh only for r,z gates
    if (pos < 72) {
      uint2 pk;
      pk.x = (unsigned)f2bf(acc[0] + bi[0] + foldh * bh4[0]) |
             ((unsigned)f2bf(acc[1] + bi[1] + foldh * bh4[1]) << 16);
      pk.y = (unsigned)f2bf(acc[2] + bi[2] + foldh * bh4[2]) |
             ((unsigned)f2bf(acc[3] + bi[3] + foldh * bh4[3]) << 16);
      *(uint2*)(sXGP + pos * XGP_STRIDE + jt * 32 + lg * 8) = pk;
    }
  }
  __syncthreads();

  // ---- hoist W fragments (ts-invariant) into registers: 24 x short8 ----
  const int swz = (c & 7) << 4;
  short8 wreg[12][2];
#pragma unroll
  for (int jt = 0; jt < 12; ++jt)
#pragma unroll
    for (int kt = 0; kt < 2; ++kt)
      wreg[jt][kt] = __builtin_bit_cast(short8,
          *(const uint4*)(sW + ((((jt * 16 + c) * 128) + kt * 64 + lg * 16) ^ swz)));

  // ---- recurrence: 9 steps, no LDS writes / shuffles / barriers ----
  const int seqB = w * 16;
  const int xrow0 = seqB + c;            // this lane's sequence (local pos)

  // b_hh_n for this lane's n-gate dims (actual rows 128 + dact), loop-invariant
  f32x4 bhn[4];
#pragma unroll
  for (int dt = 0; dt < 4; ++dt)
    bhn[dt] = *(const f32x4*)(sBhh + 128 + ((dt & 1) << 5) + (lg << 3) + ((dt >> 1) << 2));

  float hfr[4][4];                       // [dt][r]: actual dim pi_row(dt, lg*4+r)
  short8 bh[2], bl[2];                   // h B-frags (hi/lo), zero-init (h0 = 0)
#pragma unroll
  for (int dt = 0; dt < 4; ++dt)
#pragma unroll
    for (int r = 0; r < 4; ++r) hfr[dt][r] = 0.f;
#pragma unroll
  for (int kt = 0; kt < 2; ++kt) {
#pragma unroll
    for (int i = 0; i < 8; ++i) { bh[kt][i] = 0; bl[kt][i] = 0; }
  }

  for (int ts = 0; ts < WS_; ++ts) {
    const int xbase = (xrow0 + ts) * XGP_STRIDE + lg * 8;
    // issue all 12 xg b64 reads up front (overlap with MFMAs)
    uint2 xg[12];
#pragma unroll
    for (int jt = 0; jt < 12; ++jt)
      xg[jt] = *(const uint2*)(sXGP + xbase + jt * 32);

#pragma unroll
    for (int dt = 0; dt < 4; ++dt) {
      f32x4 ar = {0.f, 0.f, 0.f, 0.f};
      f32x4 az = {0.f, 0.f, 0.f, 0.f};
      f32x4 an = {0.f, 0.f, 0.f, 0.f};
#pragma unroll
      for (int kt = 0; kt < 2; ++kt) {
        ar = MFMA_BF16(wreg[dt][kt],     bh[kt], ar);
        ar = MFMA_BF16(wreg[dt][kt],     bl[kt], ar);
        az = MFMA_BF16(wreg[4 + dt][kt], bh[kt], az);
        az = MFMA_BF16(wreg[4 + dt][kt], bl[kt], az);
        an = MFMA_BF16(wreg[8 + dt][kt], bh[kt], an);
        an = MFMA_BF16(wreg[8 + dt][kt], bl[kt], an);
      }
      // gates + h update for this dt (4 dims)
#pragma unroll
      for (int r = 0; r < 4; ++r) {
        const float xr = bfget(xg[dt], r);
        const float xz = bfget(xg[4 + dt], r);
        const float xn = bfget(xg[8 + dt], r);
        const float rr_ = __builtin_amdgcn_rcpf(1.f + __expf(-(xr + ar[r])));
        const float zz  = __builtin_amdgcn_rcpf(1.f + __expf(-(xz + az[r])));
        const float hn  = an[r] + bhn[dt][r];     // b_hh_n NOT folded
        const float e2  = __expf(2.f * (xn + rr_ * hn));
        const float nn  = 1.f - 2.f * __builtin_amdgcn_rcpf(1.f + e2);
        hfr[dt][r] = (1.f - zz) * nn + zz * hfr[dt][r];
      }
    }

    // pack h -> next step's B-frags (pure registers; hi + lo split)
#pragma unroll
    for (int kt = 0; kt < 2; ++kt) {
      short8 hi8, lo8;
#pragma unroll
      for (int i = 0; i < 8; ++i) {
        const float hv = (i < 4) ? hfr[kt][i] : hfr[kt + 2][i - 4];
        const unsigned short hb16 = f2bf(hv);
        hi8[i] = (short)hb16;
        lo8[i] = (short)f2bf(hv - bf2f(hb16));
      }
      bh[kt] = hi8; bl[kt] = lo8;
    }
  }

  // ---- write final hidden (un-permute dims) ----
  float* op = out + (((size_t)b * 24 + (GH_ + gset * 4 + vh)) * L_ + l0 + seqB + c) * DK_;
#pragma unroll
  for (int dt = 0; dt < 4; ++dt)
#pragma unroll
    for (int r = 0; r < 4; ++r) {
      const int dact = ((dt & 1) << 5) + (lg << 3) + ((dt >> 1) << 2) + r;
      op[dact] = hfr[dt][r];
    }
}

extern "C" void kernel_launch(void* const* d_in, const int* in_sizes, int n_in,
                              void* d_out, int out_size, void* d_ws, size_t ws_size,
                              hipStream_t stream) {
  (void)in_sizes; (void)n_in; (void)out_size;
  const float* q   = (const float*)d_in[0];
  const float* k   = (const float*)d_in[1];
  const float* v   = (const float*)d_in[2];
  const int*   msk = (const int*)d_in[3];
  const float* wih = (const float*)d_in[4];
  const float* whh = (const float*)d_in[5];
  const float* bih = (const float*)d_in[6];
  const float* bhh = (const float*)d_in[7];
  float* out = (float*)d_out;

  const int use_bits = (ws_size >= (size_t)MB_WORDS * 8) ? 1 : 0;
  unsigned long long* mb = (unsigned long long*)d_ws;

  (void)hipFuncSetAttribute((const void*)gru_kernel,
                            hipFuncAttributeMaxDynamicSharedMemorySize, GRU_LDS_BYTES);

  if (use_bits)
    maskpack_kernel<<<dim3(MB_WORDS / 256), dim3(256), 0, stream>>>(msk, mb);
  attn_kernel<<<dim3(L_ / 64, GH_, B_), dim3(256), ATTN_LDS_BYTES, stream>>>(
      q, k, v, msk, mb, use_bits, out);
  gru_kernel<<<dim3(L_ / 64, 16, B_), dim3(256), GRU_LDS_BYTES, stream>>>(
      v, wih, whh, bih, bhh, out);
}